// Round 7
// baseline (304.012 us; speedup 1.0000x reference)
//
#include <hip/hip_runtime.h>
#include <hip/hip_bf16.h>
#include <math.h>

#define S_  2048
#define H_  1024
#define NH_ 16
#define HD_ 64
#define MM  4096            // B*S
#define NB_ 2               // batch
#define NT_ (S_ / 64)       // 32 kv tiles
#define LOG2E 1.44269504088896340736f

typedef __attribute__((ext_vector_type(8))) short bf16x8;
typedef __attribute__((ext_vector_type(4))) float f32x4;
typedef __attribute__((ext_vector_type(16))) float f32x16;
typedef __attribute__((ext_vector_type(4))) unsigned short us4;
typedef __attribute__((ext_vector_type(8))) unsigned short us8;

__device__ __forceinline__ void gld_lds16(const void* g, void* l) {
    __builtin_amdgcn_global_load_lds(
        (const __attribute__((address_space(1))) unsigned int*)g,
        (__attribute__((address_space(3))) unsigned int*)l, 16, 0, 0);
}

__device__ __forceinline__ unsigned short f2bf(float f) {
    union { float f; unsigned int u; } v; v.f = f;
    unsigned int r = v.u + 0x7FFFu + ((v.u >> 16) & 1u);
    return (unsigned short)(r >> 16);
}

// packed RNE pair convert (v_cvt_pk_bf16_f32 via HIP intrinsic)
__device__ __forceinline__ unsigned pkbf(float lo, float hi) {
    __hip_bfloat162 h = __float22bfloat162_rn(make_float2(lo, hi));
    unsigned u; __builtin_memcpy(&u, &h, 4); return u;
}

__device__ __forceinline__ float exp2_fast(float x) {
    float r; asm("v_exp_f32 %0, %1" : "=v"(r) : "v"(x)); return r;
}

// ---------------------------------------------------------------------------
// fp32 -> bf16 elementwise convert (8 elems/thread)
// ---------------------------------------------------------------------------
__global__ __launch_bounds__(256)
void cvt_bf16(const float* __restrict__ s, unsigned short* __restrict__ d, int n8)
{
    int i = blockIdx.x * 256 + threadIdx.x;
    if (i >= n8) return;
    float4 a = ((const float4*)s)[i * 2];
    float4 b = ((const float4*)s)[i * 2 + 1];
    union { unsigned u[4]; us8 v; } o;
    o.u[0] = pkbf(a.x, a.y); o.u[1] = pkbf(a.z, a.w);
    o.u[2] = pkbf(b.x, b.y); o.u[3] = pkbf(b.z, b.w);
    ((us8*)d)[i] = o.v;
}

// ---------------------------------------------------------------------------
// W [K][N] fp32 -> Wt [N][K] bf16 (tiled transpose, 4 weights via blockIdx.z)
// ---------------------------------------------------------------------------
__global__ __launch_bounds__(256)
void wtr_kernel(const float* __restrict__ W0, const float* __restrict__ W1,
                const float* __restrict__ W2, const float* __restrict__ W3,
                unsigned short* __restrict__ T0, unsigned short* __restrict__ T1,
                unsigned short* __restrict__ T2, unsigned short* __restrict__ T3)
{
    __shared__ float t[32][33];
    const float* W = blockIdx.z == 0 ? W0 : blockIdx.z == 1 ? W1 : blockIdx.z == 2 ? W2 : W3;
    unsigned short* T = blockIdx.z == 0 ? T0 : blockIdx.z == 1 ? T1 : blockIdx.z == 2 ? T2 : T3;
    const int n0 = blockIdx.x * 32, k0 = blockIdx.y * 32;
    const int tx = threadIdx.x & 31, ty = threadIdx.x >> 5;   // ty 0..7
    #pragma unroll
    for (int u = 0; u < 4; u++)
        t[ty + u * 8][tx] = W[(size_t)(k0 + ty + u * 8) * H_ + n0 + tx];
    __syncthreads();
    #pragma unroll
    for (int u = 0; u < 4; u++)
        T[(size_t)(n0 + ty + u * 8) * H_ + k0 + tx] = f2bf(t[tx][ty + u * 8]);
}

// ---------------------------------------------------------------------------
// bf16 MFMA GEMM (m97 structure), unchanged.
// EPI 0: head-split bf16 [B][NH][S][HD], value=(acc+bias)*scale
// EPI 1: transposed bf16 [B][NH][HD][S]  (for V)
// EPI 2: flat fp32 [M][N] + bias
// ---------------------------------------------------------------------------
template<int EPI>
__global__ __launch_bounds__(256)
void mfma_gemm(const unsigned short* __restrict__ A, const unsigned short* __restrict__ Bt,
               const float* __restrict__ bias, void* __restrict__ out, float scale)
{
    __shared__ __align__(16) unsigned short As[128 * 64];
    __shared__ __align__(16) unsigned short Bs[128 * 64];

    const int tid = threadIdx.x;
    const int lane = tid & 63, w = tid >> 6;
    const int lane16 = lane & 15, lg = lane >> 4;
    const int wm = w & 1, wn = w >> 1;
    const int n0 = blockIdx.x * 128, m0 = blockIdx.y * 128;

    f32x4 acc[4][4];
    #pragma unroll
    for (int m = 0; m < 4; m++)
        #pragma unroll
        for (int n = 0; n < 4; n++) acc[m][n] = (f32x4){0.f, 0.f, 0.f, 0.f};

    auto stage = [&](int kt) {
        #pragma unroll
        for (int u = 0; u < 4; u++) {
            const int seg = w * 4 + u;            // 0..15
            const int L = seg * 1024 + lane * 16; // LDS byte offset
            const int row = L >> 7;               // 0..127
            const int blk = (L >> 4) & 7;
            const int goff = kt * 64 + ((blk ^ (row & 7)) << 3);  // elements
            gld_lds16(A  + (size_t)(m0 + row) * 1024 + goff, (char*)As + L);
            gld_lds16(Bt + (size_t)(n0 + row) * 1024 + goff, (char*)Bs + L);
        }
    };

    stage(0);
    for (int kt = 0; kt < 16; kt++) {
        __syncthreads();
        #pragma unroll
        for (int ks = 0; ks < 2; ks++) {
            const int kb = ks * 64 + lg * 16;     // k byte offset within row
            bf16x8 a[4], b[4];
            #pragma unroll
            for (int m = 0; m < 4; m++) {
                const int row = wm * 64 + m * 16 + lane16;
                a[m] = *(const bf16x8*)((const char*)As + row * 128 + (kb ^ ((row & 7) << 4)));
            }
            #pragma unroll
            for (int n = 0; n < 4; n++) {
                const int row = wn * 64 + n * 16 + lane16;
                b[n] = *(const bf16x8*)((const char*)Bs + row * 128 + (kb ^ ((row & 7) << 4)));
            }
            #pragma unroll
            for (int m = 0; m < 4; m++)
                #pragma unroll
                for (int n = 0; n < 4; n++)
                    acc[m][n] = __builtin_amdgcn_mfma_f32_16x16x32_bf16(a[m], b[n], acc[m][n], 0, 0, 0);
        }
        __syncthreads();
        if (kt + 1 < 16) stage(kt + 1);
    }

    #pragma unroll
    for (int n = 0; n < 4; n++) {
        const int col = n0 + wn * 64 + n * 16 + lane16;
        const float bs = bias[col];
        #pragma unroll
        for (int m = 0; m < 4; m++) {
            const int rowb = m0 + wm * 64 + m * 16 + lg * 4;
            if (EPI == 0) {
                const int nh = col >> 6, hd = col & 63;
                #pragma unroll
                for (int j = 0; j < 4; j++) {
                    const int row = rowb + j;
                    const int bb = row >> 11, s = row & 2047;
                    ((unsigned short*)out)[((((size_t)bb * NH_ + nh) * S_ + s) << 6) + hd] =
                        f2bf((acc[m][n][j] + bs) * scale);
                }
            } else if (EPI == 1) {
                const int nh = col >> 6, hd = col & 63;
                const int bb = rowb >> 11, s = rowb & 2047;
                us4 o;
                #pragma unroll
                for (int j = 0; j < 4; j++) o[j] = f2bf(acc[m][n][j] + bs);
                *(us4*)&((unsigned short*)out)[((((size_t)bb * NH_ + nh) * HD_ + hd) << 11) + s] = o;
            } else {
                #pragma unroll
                for (int j = 0; j < 4; j++)
                    ((float*)out)[(size_t)(rowb + j) * H_ + col] = acc[m][n][j] + bs;
            }
        }
    }
}

// ---------------------------------------------------------------------------
// bf16 MFMA flash attention, swapped-QK^T + in-register softmax.
// ONE WAVE PER BLOCK (32 q-rows), no barriers. K/V/mask read directly from
// global (L2-resident per head) into register fragments; K+mask prefetched
// one tile ahead (named double buffers), V issued at tile top. Only LDS use
// is the 4KB wave-private P^T round-trip (XOR-swizzled).
// qh: [B][NH][S][64] bf16 pre-scaled by 0.125*log2e. kh: same layout.
// vt: [B][NH][64][S] bf16 (V^T). mask: [B][S][S] fp32. ao: [B][S][H] bf16.
// ---------------------------------------------------------------------------
__global__ __launch_bounds__(64, 2)
void mfma_attn(const unsigned short* __restrict__ qh, const unsigned short* __restrict__ kh,
               const unsigned short* __restrict__ vt, const float* __restrict__ mask,
               unsigned short* __restrict__ ao)
{
    __shared__ __align__(16) unsigned short St[32 * 64];   // [q][kv] bf16, swizzled

    const int lane = threadIdx.x & 63;
    const int l31 = lane & 31, lg2 = lane >> 5;

    // XCD-bijective swizzle: 2048 blocks, 8 XCDs, 256 per chunk; qt fastest
    // -> each XCD works on 4 consecutive (h,b) heads (2MB KV, L2-fits).
    const int id = blockIdx.x;
    const int swz = (id & 7) * 256 + (id >> 3);
    const int qt = swz & 63, h = (swz >> 6) & 15, bz = swz >> 10;
    const int q0 = qt * 32;
    const int q = q0 + l31;                           // this lane's q row

    const unsigned short* Qb = qh + ((size_t)(bz * NH_ + h) * S_) * HD_;
    const unsigned short* Kb = kh + ((size_t)(bz * NH_ + h) * S_) * HD_;
    const unsigned short* Vb = vt + ((size_t)(bz * NH_ + h) * HD_) * S_;
    const float* Mlane = mask + ((size_t)bz * S_ + q) * S_;

    // ---- Q fragments straight from global (col q=l31, k=d slice) ----
    bf16x8 qfrag[4];
    #pragma unroll
    for (int s = 0; s < 4; s++)
        qfrag[s] = *(const bf16x8*)(Qb + (size_t)q * HD_ + s * 16 + lg2 * 8);

    // ---- register-fragment loaders (global, frag-shaped) ----
    bf16x8 kA[8], kB[8], vC[8];
    float4 mA[8], mB[8];
    auto loadK = [&](int t, bf16x8 (&kr)[8]) {
        #pragma unroll
        for (int bb = 0; bb < 2; bb++)
            #pragma unroll
            for (int s = 0; s < 4; s++)
                kr[bb * 4 + s] = *(const bf16x8*)(Kb + (size_t)(t * 64 + bb * 32 + l31) * HD_ +
                                                  s * 16 + lg2 * 8);
    };
    auto loadM = [&](int t, float4 (&mr)[8]) {
        #pragma unroll
        for (int bb = 0; bb < 2; bb++)
            #pragma unroll
            for (int m = 0; m < 4; m++)
                mr[bb * 4 + m] = *(const float4*)(Mlane + t * 64 + bb * 32 + m * 8 + lg2 * 4);
    };
    auto loadV = [&](int t, bf16x8 (&vr)[8]) {
        #pragma unroll
        for (int db = 0; db < 2; db++)
            #pragma unroll
            for (int s = 0; s < 4; s++)
                vr[db * 4 + s] = *(const bf16x8*)(Vb + (size_t)(db * 32 + l31) * S_ +
                                                  t * 64 + s * 16 + lg2 * 8);
    };

    f32x16 oacc[2];
    #pragma unroll
    for (int db = 0; db < 2; db++)
        #pragma unroll
        for (int i = 0; i < 16; i++) oacc[db][i] = 0.f;
    float m_run = -3.0e38f, l_run = 0.f;

    loadK(0, kA); loadM(0, mA);

    auto tile = [&](int t, bf16x8 (&Kc)[8], float4 (&Mc)[8],
                    bf16x8 (&Kn)[8], float4 (&Mn)[8]) {
        // V for this tile (consumed ~end of tile); next tile's K + mask
        loadV(t, vC);
        if (t + 1 < NT_) { loadK(t + 1, Kn); loadM(t + 1, Mn); }

        // ---- QK^T (S^T[kv][q]) from registers ----
        f32x16 sc[2];
        #pragma unroll
        for (int bb = 0; bb < 2; bb++) {
            f32x16 a;
            #pragma unroll
            for (int i = 0; i < 16; i++) a[i] = 0.f;
            #pragma unroll
            for (int s = 0; s < 4; s++)
                a = __builtin_amdgcn_mfma_f32_32x32x16_bf16(Kc[bb * 4 + s], qfrag[s], a, 0, 0, 0);
            sc[bb] = a;
        }

        // ---- mask add (base-2 domain) ----
        #pragma unroll
        for (int bb = 0; bb < 2; bb++)
            #pragma unroll
            for (int m = 0; m < 4; m++) {
                sc[bb][m * 4 + 0] = fmaf(Mc[bb * 4 + m].x, LOG2E, sc[bb][m * 4 + 0]);
                sc[bb][m * 4 + 1] = fmaf(Mc[bb * 4 + m].y, LOG2E, sc[bb][m * 4 + 1]);
                sc[bb][m * 4 + 2] = fmaf(Mc[bb * 4 + m].z, LOG2E, sc[bb][m * 4 + 2]);
                sc[bb][m * 4 + 3] = fmaf(Mc[bb * 4 + m].w, LOG2E, sc[bb][m * 4 + 3]);
            }

        // ---- row max (in-register tree + cross-half via shfl) ----
        float t8[8];
        #pragma unroll
        for (int i = 0; i < 8; i++)
            t8[i] = fmaxf(fmaxf(sc[0][i], sc[0][i + 8]), fmaxf(sc[1][i], sc[1][i + 8]));
        float mloc = fmaxf(fmaxf(fmaxf(t8[0], t8[1]), fmaxf(t8[2], t8[3])),
                           fmaxf(fmaxf(t8[4], t8[5]), fmaxf(t8[6], t8[7])));
        const float mtile = fmaxf(mloc, __shfl_xor(mloc, 32, 64));

        // ---- defer-max (T13) ----
        float mnew;
        if (__all(mtile <= m_run + 8.f)) {
            mnew = m_run;
        } else {
            mnew = fmaxf(m_run, mtile);
            const float corr = exp2_fast(m_run - mnew);
            l_run *= corr;
            #pragma unroll
            for (int db = 0; db < 2; db++)
                #pragma unroll
                for (int i = 0; i < 16; i++) oacc[db][i] *= corr;
        }
        m_run = mnew;

        // ---- exp + row sum ----
        #pragma unroll
        for (int bb = 0; bb < 2; bb++)
            #pragma unroll
            for (int i = 0; i < 16; i++)
                sc[bb][i] = exp2_fast(sc[bb][i] - mnew);
        float s8[8];
        #pragma unroll
        for (int i = 0; i < 8; i++)
            s8[i] = (sc[0][i] + sc[0][i + 8]) + (sc[1][i] + sc[1][i + 8]);
        float sloc = ((s8[0] + s8[1]) + (s8[2] + s8[3])) + ((s8[4] + s8[5]) + (s8[6] + s8[7]));
        l_run += sloc + __shfl_xor(sloc, 32, 64);

        // ---- P^T -> LDS (wave-private rows; packed pairs) ----
        #pragma unroll
        for (int bb = 0; bb < 2; bb++)
            #pragma unroll
            for (int r = 0; r < 16; r += 2) {
                const unsigned pv = pkbf(sc[bb][r], sc[bb][r + 1]);
                const int kvb = bb * 64 + 2 * (r & 3) + 16 * (r >> 2) + 8 * lg2;  // byte
                *(unsigned*)((char*)St + l31 * 128 + (kvb ^ ((l31 & 7) << 4))) = pv;
            }

        // ---- read P^T B-frags (same contiguous slot addressing as V) ----
        bf16x8 pfrag[4];
        #pragma unroll
        for (int s = 0; s < 4; s++)
            pfrag[s] = *(const bf16x8*)((const char*)St + l31 * 128 +
                                        ((s * 32 + lg2 * 16) ^ ((l31 & 7) << 4)));

        // ---- PV: O^T[d][q] += V^T-frag x P^T-frag ----
        #pragma unroll
        for (int s = 0; s < 4; s++)
            #pragma unroll
            for (int db = 0; db < 2; db++)
                oacc[db] = __builtin_amdgcn_mfma_f32_32x32x16_bf16(vC[db * 4 + s], pfrag[s],
                                                                   oacc[db], 0, 0, 0);
    };

    for (int tt = 0; tt < NT_; tt += 2) {
        tile(tt,     kA, mA, kB, mB);
        tile(tt + 1, kB, mB, kA, mA);
    }

    // ---- epilogue: O[q][d] = O^T/l ----
    const float inv = 1.0f / l_run;
    unsigned short* aoq = ao + ((size_t)(bz * S_ + q)) * H_ + h * HD_;
    #pragma unroll
    for (int db = 0; db < 2; db++)
        #pragma unroll
        for (int m = 0; m < 4; m++) {
            us4 o = { f2bf(oacc[db][m * 4 + 0] * inv), f2bf(oacc[db][m * 4 + 1] * inv),
                      f2bf(oacc[db][m * 4 + 2] * inv), f2bf(oacc[db][m * 4 + 3] * inv) };
            *(us4*)&aoq[db * 32 + m * 8 + lg2 * 4] = o;
        }
}

// ---------------------------------------------------------------------------
extern "C" void kernel_launch(void* const* d_in, const int* in_sizes, int n_in,
                              void* d_out, int out_size, void* d_ws, size_t ws_size,
                              hipStream_t stream)
{
    (void)in_sizes; (void)n_in; (void)out_size; (void)ws_size;

    const float* query = (const float*)d_in[0];
    const float* key   = (const float*)d_in[1];
    const float* value = (const float*)d_in[2];
    const float* mask  = (const float*)d_in[3];
    const float* Wq    = (const float*)d_in[4];
    const float* bq    = (const float*)d_in[5];
    const float* Wk    = (const float*)d_in[6];
    const float* bk    = (const float*)d_in[7];
    const float* Wv    = (const float*)d_in[8];
    const float* bv    = (const float*)d_in[9];
    const float* Wo    = (const float*)d_in[10];
    const float* bo    = (const float*)d_in[11];

    unsigned short* ws = (unsigned short*)d_ws;
    const size_t MH = (size_t)MM * H_;       // 4 Mi elems
    const size_t WW = (size_t)H_ * H_;       // 1 Mi elems
    unsigned short* Xq  = ws;
    unsigned short* Xk  = Xq + MH;
    unsigned short* Xv  = Xk + MH;
    unsigned short* Wtq = Xv + MH;
    unsigned short* Wtk = Wtq + WW;
    unsigned short* Wtv = Wtk + WW;
    unsigned short* Wto = Wtv + WW;
    unsigned short* qh  = Wto + WW;
    unsigned short* kh  = qh + MH;
    unsigned short* vt  = kh + MH;
    unsigned short* ao  = vt + MH;

    const int n8 = (int)(MH / 8);            // 524288
    cvt_bf16<<<n8 / 256, 256, 0, stream>>>(query, Xq, n8);
    cvt_bf16<<<n8 / 256, 256, 0, stream>>>(key,   Xk, n8);
    cvt_bf16<<<n8 / 256, 256, 0, stream>>>(value, Xv, n8);
    wtr_kernel<<<dim3(32, 32, 4), 256, 0, stream>>>(Wq, Wk, Wv, Wo, Wtq, Wtk, Wtv, Wto);

    dim3 gg(8, 32);   // N/128, M/128
    mfma_gemm<0><<<gg, 256, 0, stream>>>(Xq, Wtq, bq, qh, 0.125f * LOG2E);
    mfma_gemm<0><<<gg, 256, 0, stream>>>(Xk, Wtk, bk, kh, 1.0f);
    mfma_gemm<1><<<gg, 256, 0, stream>>>(Xv, Wtv, bv, vt, 1.0f);

    mfma_attn<<<dim3(S_ / 32 * NH_ * NB_), 64, 0, stream>>>(qh, kh, vt, mask, ao);

    mfma_gemm<2><<<gg, 256, 0, stream>>>(ao, Wto, bo, d_out, 1.0f);
}

// Round 8
// 173.618 us; speedup vs baseline: 1.7510x; 1.7510x over previous
//
#include <hip/hip_runtime.h>
#include <hip/hip_bf16.h>
#include <math.h>

#define S_  2048
#define H_  1024
#define NH_ 16
#define HD_ 64
#define MM  4096            // B*S
#define NB_ 2               // batch
#define NT_ (S_ / 64)       // 32 kv tiles
#define LOG2E 1.44269504088896340736f
#define SMFIX 32.0f         // fixed softmax max (base-2 units); |sc| < 30 @6sigma

typedef __attribute__((ext_vector_type(8))) short bf16x8;
typedef __attribute__((ext_vector_type(4))) float f32x4;
typedef __attribute__((ext_vector_type(16))) float f32x16;
typedef __attribute__((ext_vector_type(4))) unsigned short us4;
typedef __attribute__((ext_vector_type(8))) unsigned short us8;
typedef __attribute__((ext_vector_type(2))) unsigned uns2;

__device__ __forceinline__ void gld_lds16(const void* g, void* l) {
    __builtin_amdgcn_global_load_lds(
        (const __attribute__((address_space(1))) unsigned int*)g,
        (__attribute__((address_space(3))) unsigned int*)l, 16, 0, 0);
}

__device__ __forceinline__ unsigned short f2bf(float f) {
    union { float f; unsigned int u; } v; v.f = f;
    unsigned int r = v.u + 0x7FFFu + ((v.u >> 16) & 1u);
    return (unsigned short)(r >> 16);
}

// packed RNE pair convert (v_cvt_pk_bf16_f32 via HIP intrinsic)
__device__ __forceinline__ unsigned pkbf(float lo, float hi) {
    __hip_bfloat162 h = __float22bfloat162_rn(make_float2(lo, hi));
    unsigned u; __builtin_memcpy(&u, &h, 4); return u;
}

__device__ __forceinline__ float exp2_fast(float x) {
    float r; asm("v_exp_f32 %0, %1" : "=v"(r) : "v"(x)); return r;
}

// ---------------------------------------------------------------------------
// fp32 -> bf16 convert, 3 arrays in one launch (blockIdx.y selects)
// ---------------------------------------------------------------------------
__global__ __launch_bounds__(256)
void cvt_bf16_3(const float* __restrict__ s0, const float* __restrict__ s1,
                const float* __restrict__ s2, unsigned short* __restrict__ d0,
                unsigned short* __restrict__ d1, unsigned short* __restrict__ d2,
                int n8)
{
    const int z = blockIdx.y;
    const float* s = z == 0 ? s0 : z == 1 ? s1 : s2;
    unsigned short* d = z == 0 ? d0 : z == 1 ? d1 : d2;
    int i = blockIdx.x * 256 + threadIdx.x;
    if (i >= n8) return;
    float4 a = ((const float4*)s)[i * 2];
    float4 b = ((const float4*)s)[i * 2 + 1];
    union { unsigned u[4]; us8 v; } o;
    o.u[0] = pkbf(a.x, a.y); o.u[1] = pkbf(a.z, a.w);
    o.u[2] = pkbf(b.x, b.y); o.u[3] = pkbf(b.z, b.w);
    ((us8*)d)[i] = o.v;
}

// ---------------------------------------------------------------------------
// W [K][N] fp32 -> Wt [N][K] bf16 (tiled transpose, 4 weights via blockIdx.z)
// ---------------------------------------------------------------------------
__global__ __launch_bounds__(256)
void wtr_kernel(const float* __restrict__ W0, const float* __restrict__ W1,
                const float* __restrict__ W2, const float* __restrict__ W3,
                unsigned short* __restrict__ T0, unsigned short* __restrict__ T1,
                unsigned short* __restrict__ T2, unsigned short* __restrict__ T3)
{
    __shared__ float t[32][33];
    const float* W = blockIdx.z == 0 ? W0 : blockIdx.z == 1 ? W1 : blockIdx.z == 2 ? W2 : W3;
    unsigned short* T = blockIdx.z == 0 ? T0 : blockIdx.z == 1 ? T1 : blockIdx.z == 2 ? T2 : T3;
    const int n0 = blockIdx.x * 32, k0 = blockIdx.y * 32;
    const int tx = threadIdx.x & 31, ty = threadIdx.x >> 5;   // ty 0..7
    #pragma unroll
    for (int u = 0; u < 4; u++)
        t[ty + u * 8][tx] = W[(size_t)(k0 + ty + u * 8) * H_ + n0 + tx];
    __syncthreads();
    #pragma unroll
    for (int u = 0; u < 4; u++)
        T[(size_t)(n0 + ty + u * 8) * H_ + k0 + tx] = f2bf(t[tx][ty + u * 8]);
}

// ---------------------------------------------------------------------------
// bf16 MFMA GEMM body (m97 structure), runtime epilogue select.
// epi 0: head-split bf16 [B][NH][S][HD], value=(acc+bias)*scale
// epi 1: transposed bf16 [B][NH][HD][S]  (for V)
// epi 2: flat fp32 [M][N] + bias
// ---------------------------------------------------------------------------
__device__ __forceinline__
void gemm_body(const unsigned short* __restrict__ A, const unsigned short* __restrict__ Bt,
               const float* __restrict__ bias, void* __restrict__ out, float scale, int epi)
{
    __shared__ __align__(16) unsigned short As[128 * 64];
    __shared__ __align__(16) unsigned short Bs[128 * 64];

    const int tid = threadIdx.x;
    const int lane = tid & 63, w = tid >> 6;
    const int lane16 = lane & 15, lg = lane >> 4;
    const int wm = w & 1, wn = w >> 1;
    const int n0 = blockIdx.x * 128, m0 = blockIdx.y * 128;

    f32x4 acc[4][4];
    #pragma unroll
    for (int m = 0; m < 4; m++)
        #pragma unroll
        for (int n = 0; n < 4; n++) acc[m][n] = (f32x4){0.f, 0.f, 0.f, 0.f};

    auto stage = [&](int kt) {
        #pragma unroll
        for (int u = 0; u < 4; u++) {
            const int seg = w * 4 + u;            // 0..15
            const int L = seg * 1024 + lane * 16; // LDS byte offset
            const int row = L >> 7;               // 0..127
            const int blk = (L >> 4) & 7;
            const int goff = kt * 64 + ((blk ^ (row & 7)) << 3);  // elements
            gld_lds16(A  + (size_t)(m0 + row) * 1024 + goff, (char*)As + L);
            gld_lds16(Bt + (size_t)(n0 + row) * 1024 + goff, (char*)Bs + L);
        }
    };

    stage(0);
    for (int kt = 0; kt < 16; kt++) {
        __syncthreads();
        #pragma unroll
        for (int ks = 0; ks < 2; ks++) {
            const int kb = ks * 64 + lg * 16;     // k byte offset within row
            bf16x8 a[4], b[4];
            #pragma unroll
            for (int m = 0; m < 4; m++) {
                const int row = wm * 64 + m * 16 + lane16;
                a[m] = *(const bf16x8*)((const char*)As + row * 128 + (kb ^ ((row & 7) << 4)));
            }
            #pragma unroll
            for (int n = 0; n < 4; n++) {
                const int row = wn * 64 + n * 16 + lane16;
                b[n] = *(const bf16x8*)((const char*)Bs + row * 128 + (kb ^ ((row & 7) << 4)));
            }
            #pragma unroll
            for (int m = 0; m < 4; m++)
                #pragma unroll
                for (int n = 0; n < 4; n++)
                    acc[m][n] = __builtin_amdgcn_mfma_f32_16x16x32_bf16(a[m], b[n], acc[m][n], 0, 0, 0);
        }
        __syncthreads();
        if (kt + 1 < 16) stage(kt + 1);
    }

    #pragma unroll
    for (int n = 0; n < 4; n++) {
        const int col = n0 + wn * 64 + n * 16 + lane16;
        const float bs = bias[col];
        #pragma unroll
        for (int m = 0; m < 4; m++) {
            const int rowb = m0 + wm * 64 + m * 16 + lg * 4;
            if (epi == 0) {
                const int nh = col >> 6, hd = col & 63;
                #pragma unroll
                for (int j = 0; j < 4; j++) {
                    const int row = rowb + j;
                    const int bb = row >> 11, s = row & 2047;
                    ((unsigned short*)out)[((((size_t)bb * NH_ + nh) * S_ + s) << 6) + hd] =
                        f2bf((acc[m][n][j] + bs) * scale);
                }
            } else if (epi == 1) {
                const int nh = col >> 6, hd = col & 63;
                const int bb = rowb >> 11, s = rowb & 2047;
                us4 o;
                #pragma unroll
                for (int j = 0; j < 4; j++) o[j] = f2bf(acc[m][n][j] + bs);
                *(us4*)&((unsigned short*)out)[((((size_t)bb * NH_ + nh) * HD_ + hd) << 11) + s] = o;
            } else {
                #pragma unroll
                for (int j = 0; j < 4; j++)
                    ((float*)out)[(size_t)(rowb + j) * H_ + col] = acc[m][n][j] + bs;
            }
        }
    }
}

// QKV in one launch: blockIdx.z selects {A, Wt, bias, out, scale, epi}
__global__ __launch_bounds__(256)
void gemm_qkv(const unsigned short* __restrict__ Xq, const unsigned short* __restrict__ Xk,
              const unsigned short* __restrict__ Xv,
              const unsigned short* __restrict__ Wtq, const unsigned short* __restrict__ Wtk,
              const unsigned short* __restrict__ Wtv,
              const float* __restrict__ bq, const float* __restrict__ bk,
              const float* __restrict__ bv,
              unsigned short* __restrict__ qh, unsigned short* __restrict__ kh,
              unsigned short* __restrict__ vt, float qscale)
{
    const int z = blockIdx.z;
    const unsigned short* A  = z == 0 ? Xq : z == 1 ? Xk : Xv;
    const unsigned short* Bt = z == 0 ? Wtq : z == 1 ? Wtk : Wtv;
    const float* bias        = z == 0 ? bq : z == 1 ? bk : bv;
    void* out                = z == 0 ? (void*)qh : z == 1 ? (void*)kh : (void*)vt;
    gemm_body(A, Bt, bias, out, z == 0 ? qscale : 1.0f, z == 2 ? 1 : 0);
}

__global__ __launch_bounds__(256)
void gemm_out(const unsigned short* __restrict__ A, const unsigned short* __restrict__ Bt,
              const float* __restrict__ bias, float* __restrict__ out)
{
    gemm_body(A, Bt, bias, out, 1.0f, 2);
}

// ---------------------------------------------------------------------------
// bf16 MFMA flash attention, swapped-QK^T, FIXED-max softmax.
// 2 waves x 32 q-rows = 64-q tile; grid 1024 -> 4 blocks/CU (LDS 40KB).
// qh: [B][NH][S][64] bf16 pre-scaled by 0.125*log2e. kh: same layout.
// vt: [B][NH][64][S] bf16 (V^T). mask: [B][S][S] fp32. ao: [B][S][H] bf16.
// p = exp2(sc + mask*log2e - 32)  -- scores bounded (|sc|<30 @6sigma), so the
// softmax ratio is exact with a constant shift; l merges across halves once.
// ---------------------------------------------------------------------------
__global__ __launch_bounds__(128, 2)
void mfma_attn(const unsigned short* __restrict__ qh, const unsigned short* __restrict__ kh,
               const unsigned short* __restrict__ vt, const float* __restrict__ mask,
               unsigned short* __restrict__ ao)
{
    __shared__ __align__(16) unsigned short Qs[64 * 64];      // 8KB; re-used as St
    __shared__ __align__(16) unsigned short Ks[2][64 * 64];   // 16KB
    __shared__ __align__(16) unsigned short Vs[2][64 * 64];   // 16KB [d][kv]
    unsigned short* St = Qs;                                  // [q][kv] wave-private rows

    const int tid = threadIdx.x;
    const int lane = tid & 63, wq = tid >> 6;     // 2 waves
    const int l31 = lane & 31, lg2 = lane >> 5;
    const int qt = blockIdx.x, h = blockIdx.y, bz = blockIdx.z;
    const int q0 = qt * 64;

    const unsigned short* Qb = qh + (((size_t)(bz * NH_ + h) * S_) + q0) * HD_;
    const unsigned short* Kb = kh + ((size_t)(bz * NH_ + h) * S_) * HD_;
    const unsigned short* Vb = vt + ((size_t)(bz * NH_ + h) * HD_) * S_;
    const int qrow = wq * 32 + l31;                   // tile-local q row (0..63)
    const int q = q0 + qrow;                          // global q row
    const float* Mlane = mask + ((size_t)bz * S_ + q) * S_;

    // ---- stage Q (8 KB = 4 passes of 128 thr x 16 B) ----
    #pragma unroll
    for (int u = 0; u < 4; u++) {
        const int L = u * 2048 + tid * 16;
        const int row = L >> 7, blk = (L >> 4) & 7;
        gld_lds16(Qb + (size_t)row * HD_ + ((blk ^ (row & 7)) << 3), (char*)Qs + L);
    }
    // ---- K/V tile staging (8 KB each = 4 passes each) ----
    auto stageKV = [&](int t) {
        const int buf = t & 1;
        #pragma unroll
        for (int u = 0; u < 4; u++) {
            const int L = u * 2048 + tid * 16;
            const int row = L >> 7, blk = (L >> 4) & 7;   // row: kv for K, d for V
            const int off = (blk ^ (row & 7)) << 3;
            gld_lds16(Kb + (size_t)(t * 64 + row) * HD_ + off, (char*)&Ks[buf][0] + L);
            gld_lds16(Vb + (size_t)row * S_ + t * 64 + off,    (char*)&Vs[buf][0] + L);
        }
    };
    stageKV(0);

    // ---- mask loads, pre-biased: mb = mask*log2e - SMFIX ----
    float4 mA[8], mB[8];
    auto loadM = [&](int t, float4 (&mr)[8]) {
        #pragma unroll
        for (int bb = 0; bb < 2; bb++)
            #pragma unroll
            for (int m = 0; m < 4; m++) {
                float4 v = *(const float4*)(Mlane + t * 64 + bb * 32 + m * 8 + lg2 * 4);
                v.x = fmaf(v.x, LOG2E, -SMFIX);
                v.y = fmaf(v.y, LOG2E, -SMFIX);
                v.z = fmaf(v.z, LOG2E, -SMFIX);
                v.w = fmaf(v.w, LOG2E, -SMFIX);
                mr[bb * 4 + m] = v;
            }
    };
    loadM(0, mA);

    __syncthreads();

    // ---- hoist Q fragments (B-operand: col q=l31+wq*32, k=d contiguous 8) ----
    bf16x8 qfrag[4];
    #pragma unroll
    for (int s = 0; s < 4; s++)
        qfrag[s] = *(const bf16x8*)((const char*)Qs + qrow * 128 +
                                    ((s * 32 + lg2 * 16) ^ ((qrow & 7) << 4)));

    f32x16 oacc[2];
    #pragma unroll
    for (int db = 0; db < 2; db++)
        #pragma unroll
        for (int i = 0; i < 16; i++) oacc[db][i] = 0.f;
    float l_run = 0.f;

    auto tile = [&](int t, float4 (&Mc)[8], float4 (&Mn)[8]) {
        if (t) __syncthreads();        // K/V(t) staged; all waves done with buf^1
        const int buf = t & 1;

        // ---- prefetch next K/V + next mask ----
        if (t + 1 < NT_) { stageKV(t + 1); loadM(t + 1, Mn); }

        // ---- QK^T (S^T[kv][q]) ----
        f32x16 sc[2];
        #pragma unroll
        for (int bb = 0; bb < 2; bb++) {
            f32x16 a;
            #pragma unroll
            for (int i = 0; i < 16; i++) a[i] = 0.f;
            #pragma unroll
            for (int s = 0; s < 4; s++) {
                const int row = bb * 32 + l31;
                bf16x8 kf = *(const bf16x8*)((const char*)&Ks[buf][0] + row * 128 +
                                             ((s * 32 + lg2 * 16) ^ ((row & 7) << 4)));
                a = __builtin_amdgcn_mfma_f32_32x32x16_bf16(kf, qfrag[s], a, 0, 0, 0);
            }
            sc[bb] = a;
        }

        // ---- p = exp2(sc + mb)   (fixed max; mb pre-biased) ----
        #pragma unroll
        for (int bb = 0; bb < 2; bb++)
            #pragma unroll
            for (int m = 0; m < 4; m++) {
                sc[bb][m * 4 + 0] = exp2_fast(sc[bb][m * 4 + 0] + Mc[bb * 4 + m].x);
                sc[bb][m * 4 + 1] = exp2_fast(sc[bb][m * 4 + 1] + Mc[bb * 4 + m].y);
                sc[bb][m * 4 + 2] = exp2_fast(sc[bb][m * 4 + 2] + Mc[bb * 4 + m].z);
                sc[bb][m * 4 + 3] = exp2_fast(sc[bb][m * 4 + 3] + Mc[bb * 4 + m].w);
            }

        // ---- local row sum (half-lane only; cross-half merged in epilogue) ----
        float s8[8];
        #pragma unroll
        for (int i = 0; i < 8; i++)
            s8[i] = (sc[0][i] + sc[0][i + 8]) + (sc[1][i] + sc[1][i + 8]);
        l_run += ((s8[0] + s8[1]) + (s8[2] + s8[3])) + ((s8[4] + s8[5]) + (s8[6] + s8[7]));

        // ---- P^T -> LDS (wave-private rows; 8 x ds_write_b64) ----
        #pragma unroll
        for (int bb = 0; bb < 2; bb++)
            #pragma unroll
            for (int qd = 0; qd < 4; qd++) {
                uns2 pv = { pkbf(sc[bb][qd * 4 + 0], sc[bb][qd * 4 + 1]),
                            pkbf(sc[bb][qd * 4 + 2], sc[bb][qd * 4 + 3]) };
                const int kvb = bb * 64 + 16 * qd + 8 * lg2;   // byte, 8B-aligned
                *(uns2*)((char*)St + qrow * 128 + (kvb ^ ((qrow & 7) << 4))) = pv;
            }

        // ---- read P^T B-frags (same contiguous slot addressing as V) ----
        bf16x8 pfrag[4];
        #pragma unroll
        for (int s = 0; s < 4; s++)
            pfrag[s] = *(const bf16x8*)((const char*)St + qrow * 128 +
                                        ((s * 32 + lg2 * 16) ^ ((qrow & 7) << 4)));

        // ---- PV: O^T[d][q] += V^T-frag x P^T-frag ----
        #pragma unroll
        for (int s = 0; s < 4; s++)
            #pragma unroll
            for (int db = 0; db < 2; db++) {
                const int row = db * 32 + l31;
                bf16x8 vf = *(const bf16x8*)((const char*)&Vs[buf][0] + row * 128 +
                                             ((s * 32 + lg2 * 16) ^ ((row & 7) << 4)));
                oacc[db] = __builtin_amdgcn_mfma_f32_32x32x16_bf16(vf, pfrag[s], oacc[db], 0, 0, 0);
            }
    };

    for (int tt = 0; tt < NT_; tt += 2) {
        tile(tt,     mA, mB);
        tile(tt + 1, mB, mA);
    }

    // ---- epilogue: merge halves, O[q][d] = O^T/l ----
    l_run += __shfl_xor(l_run, 32, 64);
    const float inv = 1.0f / l_run;
    unsigned short* aoq = ao + ((size_t)(bz * S_ + q)) * H_ + h * HD_;
    #pragma unroll
    for (int db = 0; db < 2; db++)
        #pragma unroll
        for (int m = 0; m < 4; m++) {
            us4 o = { f2bf(oacc[db][m * 4 + 0] * inv), f2bf(oacc[db][m * 4 + 1] * inv),
                      f2bf(oacc[db][m * 4 + 2] * inv), f2bf(oacc[db][m * 4 + 3] * inv) };
            *(us4*)&aoq[db * 32 + m * 8 + lg2 * 4] = o;
        }
}

// ---------------------------------------------------------------------------
extern "C" void kernel_launch(void* const* d_in, const int* in_sizes, int n_in,
                              void* d_out, int out_size, void* d_ws, size_t ws_size,
                              hipStream_t stream)
{
    (void)in_sizes; (void)n_in; (void)out_size; (void)ws_size;

    const float* query = (const float*)d_in[0];
    const float* key   = (const float*)d_in[1];
    const float* value = (const float*)d_in[2];
    const float* mask  = (const float*)d_in[3];
    const float* Wq    = (const float*)d_in[4];
    const float* bq    = (const float*)d_in[5];
    const float* Wk    = (const float*)d_in[6];
    const float* bk    = (const float*)d_in[7];
    const float* Wv    = (const float*)d_in[8];
    const float* bv    = (const float*)d_in[9];
    const float* Wo    = (const float*)d_in[10];
    const float* bo    = (const float*)d_in[11];

    unsigned short* ws = (unsigned short*)d_ws;
    const size_t MH = (size_t)MM * H_;       // 4 Mi elems
    const size_t WW = (size_t)H_ * H_;       // 1 Mi elems
    unsigned short* Xq  = ws;
    unsigned short* Xk  = Xq + MH;
    unsigned short* Xv  = Xk + MH;
    unsigned short* Wtq = Xv + MH;
    unsigned short* Wtk = Wtq + WW;
    unsigned short* Wtv = Wtk + WW;
    unsigned short* Wto = Wtv + WW;
    unsigned short* qh  = Wto + WW;
    unsigned short* kh  = qh + MH;
    unsigned short* vt  = kh + MH;
    unsigned short* ao  = vt + MH;

    const int n8 = (int)(MH / 8);            // 524288
    cvt_bf16_3<<<dim3(n8 / 256, 3), 256, 0, stream>>>(query, key, value, Xq, Xk, Xv, n8);
    wtr_kernel<<<dim3(32, 32, 4), 256, 0, stream>>>(Wq, Wk, Wv, Wo, Wtq, Wtk, Wtv, Wto);

    gemm_qkv<<<dim3(8, 32, 3), 256, 0, stream>>>(Xq, Xk, Xv, Wtq, Wtk, Wtv,
                                                 bq, bk, bv, qh, kh, vt, 0.125f * LOG2E);

    mfma_attn<<<dim3(S_ / 64, NH_, NB_), 128, 0, stream>>>(qh, kh, vt, mask, ao);

    gemm_out<<<dim3(8, 32), 256, 0, stream>>>(ao, Wto, bo, (float*)d_out);
}

// Round 10
// 168.671 us; speedup vs baseline: 1.8024x; 1.0293x over previous
//
#include <hip/hip_runtime.h>
#include <hip/hip_bf16.h>
#include <math.h>

#define S_  2048
#define H_  1024
#define NH_ 16
#define HD_ 64
#define MM  4096            // B*S
#define NB_ 2               // batch
#define NT_ (S_ / 64)       // 32 kv tiles
#define LOG2E 1.44269504088896340736f
#define SMFIX 32.0f         // fixed softmax max (base-2 units); |sc| < 30 @6sigma

typedef __attribute__((ext_vector_type(8))) short bf16x8;
typedef __attribute__((ext_vector_type(4))) float f32x4;
typedef __attribute__((ext_vector_type(4))) unsigned short us4;
typedef __attribute__((ext_vector_type(8))) unsigned short us8;

__device__ __forceinline__ void gld_lds16(const void* g, void* l) {
    __builtin_amdgcn_global_load_lds(
        (const __attribute__((address_space(1))) unsigned int*)g,
        (__attribute__((address_space(3))) unsigned int*)l, 16, 0, 0);
}

__device__ __forceinline__ unsigned short f2bf(float f) {
    union { float f; unsigned int u; } v; v.f = f;
    unsigned int r = v.u + 0x7FFFu + ((v.u >> 16) & 1u);
    return (unsigned short)(r >> 16);
}

// packed RNE pair convert (v_cvt_pk_bf16_f32 via HIP intrinsic)
__device__ __forceinline__ unsigned pkbf(float lo, float hi) {
    __hip_bfloat162 h = __float22bfloat162_rn(make_float2(lo, hi));
    unsigned u; __builtin_memcpy(&u, &h, 4); return u;
}

__device__ __forceinline__ float exp2_fast(float x) {
    float r; asm("v_exp_f32 %0, %1" : "=v"(r) : "v"(x)); return r;
}

// ---------------------------------------------------------------------------
// fp32 -> bf16 convert, 3 arrays in one launch (blockIdx.y selects)
// ---------------------------------------------------------------------------
__global__ __launch_bounds__(256)
void cvt_bf16_3(const float* __restrict__ s0, const float* __restrict__ s1,
                const float* __restrict__ s2, unsigned short* __restrict__ d0,
                unsigned short* __restrict__ d1, unsigned short* __restrict__ d2,
                int n8)
{
    const int z = blockIdx.y;
    const float* s = z == 0 ? s0 : z == 1 ? s1 : s2;
    unsigned short* d = z == 0 ? d0 : z == 1 ? d1 : d2;
    int i = blockIdx.x * 256 + threadIdx.x;
    if (i >= n8) return;
    float4 a = ((const float4*)s)[i * 2];
    float4 b = ((const float4*)s)[i * 2 + 1];
    union { unsigned u[4]; us8 v; } o;
    o.u[0] = pkbf(a.x, a.y); o.u[1] = pkbf(a.z, a.w);
    o.u[2] = pkbf(b.x, b.y); o.u[3] = pkbf(b.z, b.w);
    ((us8*)d)[i] = o.v;
}

// ---------------------------------------------------------------------------
// W [K][N] fp32 -> Wt [N][K] bf16 (tiled transpose, 4 weights via blockIdx.z)
// ---------------------------------------------------------------------------
__global__ __launch_bounds__(256)
void wtr_kernel(const float* __restrict__ W0, const float* __restrict__ W1,
                const float* __restrict__ W2, const float* __restrict__ W3,
                unsigned short* __restrict__ T0, unsigned short* __restrict__ T1,
                unsigned short* __restrict__ T2, unsigned short* __restrict__ T3)
{
    __shared__ float t[32][33];
    const float* W = blockIdx.z == 0 ? W0 : blockIdx.z == 1 ? W1 : blockIdx.z == 2 ? W2 : W3;
    unsigned short* T = blockIdx.z == 0 ? T0 : blockIdx.z == 1 ? T1 : blockIdx.z == 2 ? T2 : T3;
    const int n0 = blockIdx.x * 32, k0 = blockIdx.y * 32;
    const int tx = threadIdx.x & 31, ty = threadIdx.x >> 5;   // ty 0..7
    #pragma unroll
    for (int u = 0; u < 4; u++)
        t[ty + u * 8][tx] = W[(size_t)(k0 + ty + u * 8) * H_ + n0 + tx];
    __syncthreads();
    #pragma unroll
    for (int u = 0; u < 4; u++)
        T[(size_t)(n0 + ty + u * 8) * H_ + k0 + tx] = f2bf(t[tx][ty + u * 8]);
}

// ---------------------------------------------------------------------------
// bf16 MFMA GEMM body (m97 structure), runtime epilogue select.
// epi 0: head-split bf16 [B][NH][S][HD], value=(acc+bias)*scale
// epi 1: transposed bf16 [B][NH][HD][S]  (for V)
// epi 2: flat fp32 [M][N] + bias
// ---------------------------------------------------------------------------
__device__ __forceinline__
void gemm_body(const unsigned short* __restrict__ A, const unsigned short* __restrict__ Bt,
               const float* __restrict__ bias, void* __restrict__ out, float scale, int epi)
{
    __shared__ __align__(16) unsigned short As[128 * 64];
    __shared__ __align__(16) unsigned short Bs[128 * 64];

    const int tid = threadIdx.x;
    const int lane = tid & 63, w = tid >> 6;
    const int lane16 = lane & 15, lg = lane >> 4;
    const int wm = w & 1, wn = w >> 1;
    const int n0 = blockIdx.x * 128, m0 = blockIdx.y * 128;

    f32x4 acc[4][4];
    #pragma unroll
    for (int m = 0; m < 4; m++)
        #pragma unroll
        for (int n = 0; n < 4; n++) acc[m][n] = (f32x4){0.f, 0.f, 0.f, 0.f};

    auto stage = [&](int kt) {
        #pragma unroll
        for (int u = 0; u < 4; u++) {
            const int seg = w * 4 + u;            // 0..15
            const int L = seg * 1024 + lane * 16; // LDS byte offset
            const int row = L >> 7;               // 0..127
            const int blk = (L >> 4) & 7;
            const int goff = kt * 64 + ((blk ^ (row & 7)) << 3);  // elements
            gld_lds16(A  + (size_t)(m0 + row) * 1024 + goff, (char*)As + L);
            gld_lds16(Bt + (size_t)(n0 + row) * 1024 + goff, (char*)Bs + L);
        }
    };

    stage(0);
    for (int kt = 0; kt < 16; kt++) {
        __syncthreads();
        #pragma unroll
        for (int ks = 0; ks < 2; ks++) {
            const int kb = ks * 64 + lg * 16;     // k byte offset within row
            bf16x8 a[4], b[4];
            #pragma unroll
            for (int m = 0; m < 4; m++) {
                const int row = wm * 64 + m * 16 + lane16;
                a[m] = *(const bf16x8*)((const char*)As + row * 128 + (kb ^ ((row & 7) << 4)));
            }
            #pragma unroll
            for (int n = 0; n < 4; n++) {
                const int row = wn * 64 + n * 16 + lane16;
                b[n] = *(const bf16x8*)((const char*)Bs + row * 128 + (kb ^ ((row & 7) << 4)));
            }
            #pragma unroll
            for (int m = 0; m < 4; m++)
                #pragma unroll
                for (int n = 0; n < 4; n++)
                    acc[m][n] = __builtin_amdgcn_mfma_f32_16x16x32_bf16(a[m], b[n], acc[m][n], 0, 0, 0);
        }
        __syncthreads();
        if (kt + 1 < 16) stage(kt + 1);
    }

    #pragma unroll
    for (int n = 0; n < 4; n++) {
        const int col = n0 + wn * 64 + n * 16 + lane16;
        const float bs = bias[col];
        #pragma unroll
        for (int m = 0; m < 4; m++) {
            const int rowb = m0 + wm * 64 + m * 16 + lg * 4;
            if (epi == 0) {
                const int nh = col >> 6, hd = col & 63;
                #pragma unroll
                for (int j = 0; j < 4; j++) {
                    const int row = rowb + j;
                    const int bb = row >> 11, s = row & 2047;
                    ((unsigned short*)out)[((((size_t)bb * NH_ + nh) * S_ + s) << 6) + hd] =
                        f2bf((acc[m][n][j] + bs) * scale);
                }
            } else if (epi == 1) {
                const int nh = col >> 6, hd = col & 63;
                const int bb = rowb >> 11, s = rowb & 2047;
                us4 o;
                #pragma unroll
                for (int j = 0; j < 4; j++) o[j] = f2bf(acc[m][n][j] + bs);
                *(us4*)&((unsigned short*)out)[((((size_t)bb * NH_ + nh) * HD_ + hd) << 11) + s] = o;
            } else {
                #pragma unroll
                for (int j = 0; j < 4; j++)
                    ((float*)out)[(size_t)(rowb + j) * H_ + col] = acc[m][n][j] + bs;
            }
        }
    }
}

// QKV in one launch: blockIdx.z selects {A, Wt, bias, out, scale, epi}
__global__ __launch_bounds__(256)
void gemm_qkv(const unsigned short* __restrict__ Xq, const unsigned short* __restrict__ Xk,
              const unsigned short* __restrict__ Xv,
              const unsigned short* __restrict__ Wtq, const unsigned short* __restrict__ Wtk,
              const unsigned short* __restrict__ Wtv,
              const float* __restrict__ bq, const float* __restrict__ bk,
              const float* __restrict__ bv,
              unsigned short* __restrict__ qh, unsigned short* __restrict__ kh,
              unsigned short* __restrict__ vt, float qscale)
{
    const int z = blockIdx.z;
    const unsigned short* A  = z == 0 ? Xq : z == 1 ? Xk : Xv;
    const unsigned short* Bt = z == 0 ? Wtq : z == 1 ? Wtk : Wtv;
    const float* bias        = z == 0 ? bq : z == 1 ? bk : bv;
    void* out                = z == 0 ? (void*)qh : z == 1 ? (void*)kh : (void*)vt;
    gemm_body(A, Bt, bias, out, z == 0 ? qscale : 1.0f, z == 2 ? 1 : 0);
}

__global__ __launch_bounds__(256)
void gemm_out(const unsigned short* __restrict__ A, const unsigned short* __restrict__ Bt,
              const float* __restrict__ bias, float* __restrict__ out)
{
    gemm_body(A, Bt, bias, out, 1.0f, 2);
}

// ---------------------------------------------------------------------------
// bf16 MFMA flash attention, 16x16x32 shapes, 16 q-rows/wave (4096 waves ->
// 4 waves/SIMD). Block: 4 waves x 16q = 64-q tile; KVBLK 64; K/V dbuf 32KB.
// Swapped QK: S^T[kv][q] = mfma16(K-frag, Q-frag); lane owns q=lane16,
// kv = kvt*16 + lg4*4 + j (m89-verified C layout). P^T repacked to PV B-frags
// fully in registers: cvt_pk pairs + __shfl cross-lane-group gather + select
// (element->k order identical in both PV operands, so HW k-permutation cancels).
// Fixed-max softmax (p = exp2(sc + mask*log2e - 32)); l reduced in epilogue.
// qh: [B][NH][S][64] bf16 pre-scaled by 0.125*log2e. kh: same layout.
// vt: [B][NH][64][S] bf16 (V^T). mask: [B][S][S] fp32. ao: [B][S][H] bf16.
// ---------------------------------------------------------------------------
__global__ __launch_bounds__(256, 4)
void mfma_attn(const unsigned short* __restrict__ qh, const unsigned short* __restrict__ kh,
               const unsigned short* __restrict__ vt, const float* __restrict__ mask,
               unsigned short* __restrict__ ao)
{
    __shared__ __align__(16) unsigned short Ks[2][64 * 64];   // 16KB [kv][d]
    __shared__ __align__(16) unsigned short Vs[2][64 * 64];   // 16KB [d][kv]

    const int tid = threadIdx.x;
    const int lane = tid & 63, wq = tid >> 6;      // wave 0..3
    const int l16 = lane & 15, lg4 = lane >> 4;    // lane group 0..3
    const int qt = blockIdx.x, h = blockIdx.y, bz = blockIdx.z;
    const int q = qt * 64 + wq * 16 + l16;         // this lane's q row

    const unsigned short* Kb = kh + ((size_t)(bz * NH_ + h) * S_) * HD_;
    const unsigned short* Vb = vt + ((size_t)(bz * NH_ + h) * HD_) * S_;
    const float* Mlane = mask + ((size_t)bz * S_ + q) * S_;

    // ---- Q fragments from global: B-frag col q, d = s*32 + lg4*8 + 0..7 ----
    bf16x8 qfrag[2];
    {
        const unsigned short* Qrow = qh + (((size_t)(bz * NH_ + h) * S_) + q) * HD_;
        qfrag[0] = *(const bf16x8*)(Qrow + lg4 * 8);
        qfrag[1] = *(const bf16x8*)(Qrow + 32 + lg4 * 8);
    }

    // ---- K/V tile staging (8 KB each = 2 passes of 256 thr x 16 B) ----
    auto stageKV = [&](int t) {
        const int buf = t & 1;
        #pragma unroll
        for (int u = 0; u < 2; u++) {
            const int L = u * 4096 + tid * 16;
            const int row = L >> 7, blk = (L >> 4) & 7;   // row: kv for K, d for V
            const int off = (blk ^ (row & 7)) << 3;
            gld_lds16(Kb + (size_t)(t * 64 + row) * HD_ + off, (char*)&Ks[buf][0] + L);
            gld_lds16(Vb + (size_t)row * S_ + t * 64 + off,    (char*)&Vs[buf][0] + L);
        }
    };
    stageKV(0);

    // ---- mask loads, pre-biased: mb = mask*log2e - SMFIX ----
    // lane covers kv = kvt*16 + lg4*4 + 0..3 (matches C-frag rows)
    float4 mA[4], mB[4];
    auto loadM = [&](int t, float4 (&mr)[4]) {
        #pragma unroll
        for (int kvt = 0; kvt < 4; kvt++) {
            float4 v = *(const float4*)(Mlane + t * 64 + kvt * 16 + lg4 * 4);
            v.x = fmaf(v.x, LOG2E, -SMFIX);
            v.y = fmaf(v.y, LOG2E, -SMFIX);
            v.z = fmaf(v.z, LOG2E, -SMFIX);
            v.w = fmaf(v.w, LOG2E, -SMFIX);
            mr[kvt] = v;
        }
    };
    loadM(0, mA);

    __syncthreads();   // *** drain stageKV(0) global_load_lds before first ds_read (R9 NaN fix) ***

    f32x4 oacc[4];
    #pragma unroll
    for (int dt = 0; dt < 4; dt++) oacc[dt] = (f32x4){0.f, 0.f, 0.f, 0.f};
    float l_run = 0.f;

    // repack gather lanes (constant per thread)
    const int srclA = ((lg4 & 1) * 2) * 16 + l16;   // words 0,1 source lane
    const int srclB = srclA + 16;                   // words 2,3 source lane
    const bool hi = (lg4 >> 1) != 0;

    auto tile = [&](int t, float4 (&Mc)[4], float4 (&Mn)[4]) {
        if (t) __syncthreads();        // K/V(t) staged; all waves done with buf^1
        const int buf = t & 1;

        // ---- prefetch next K/V + next mask ----
        if (t + 1 < NT_) { stageKV(t + 1); loadM(t + 1, Mn); }

        // ---- QK^T: sc[kvt] = S^T[kvt*16 + lg4*4 + j][q] ----
        f32x4 sc[4];
        #pragma unroll
        for (int kvt = 0; kvt < 4; kvt++) {
            f32x4 a = (f32x4){0.f, 0.f, 0.f, 0.f};
            #pragma unroll
            for (int s = 0; s < 2; s++) {
                const int row = kvt * 16 + l16;
                bf16x8 kf = *(const bf16x8*)((const char*)&Ks[buf][0] + row * 128 +
                                             ((s * 64 + lg4 * 16) ^ ((row & 7) << 4)));
                a = __builtin_amdgcn_mfma_f32_16x16x32_bf16(kf, qfrag[s], a, 0, 0, 0);
            }
            sc[kvt] = a;
        }

        // ---- p = exp2(sc + mb), accumulate partial l ----
        #pragma unroll
        for (int kvt = 0; kvt < 4; kvt++) {
            sc[kvt][0] = exp2_fast(sc[kvt][0] + Mc[kvt].x);
            sc[kvt][1] = exp2_fast(sc[kvt][1] + Mc[kvt].y);
            sc[kvt][2] = exp2_fast(sc[kvt][2] + Mc[kvt].z);
            sc[kvt][3] = exp2_fast(sc[kvt][3] + Mc[kvt].w);
            l_run += (sc[kvt][0] + sc[kvt][1]) + (sc[kvt][2] + sc[kvt][3]);
        }

        // ---- pack pairs: pk[kvt][p] = bf16(sc[2p], sc[2p+1]) ----
        unsigned pk0[2], pk1[2], pk2[2], pk3[2];
        pk0[0] = pkbf(sc[0][0], sc[0][1]); pk0[1] = pkbf(sc[0][2], sc[0][3]);
        pk1[0] = pkbf(sc[1][0], sc[1][1]); pk1[1] = pkbf(sc[1][2], sc[1][3]);
        pk2[0] = pkbf(sc[2][0], sc[2][1]); pk2[1] = pkbf(sc[2][2], sc[2][3]);
        pk3[0] = pkbf(sc[3][0], sc[3][1]); pk3[1] = pkbf(sc[3][2], sc[3][3]);

        // ---- repack to PV B-frags: pfrag[w], kv = w*32 + lg4*8 + 0..7 ----
        bf16x8 pfrag[2];
        {
            union { unsigned u[4]; bf16x8 v; } P;
            // w=0: candidates kvt 0 (lo) / 1 (hi)
            unsigned a0 = __shfl(pk0[0], srclA, 64), b0 = __shfl(pk1[0], srclA, 64);
            unsigned a1 = __shfl(pk0[1], srclA, 64), b1 = __shfl(pk1[1], srclA, 64);
            unsigned a2 = __shfl(pk0[0], srclB, 64), b2 = __shfl(pk1[0], srclB, 64);
            unsigned a3 = __shfl(pk0[1], srclB, 64), b3 = __shfl(pk1[1], srclB, 64);
            P.u[0] = hi ? b0 : a0;  P.u[1] = hi ? b1 : a1;
            P.u[2] = hi ? b2 : a2;  P.u[3] = hi ? b3 : a3;
            pfrag[0] = P.v;
            // w=1: candidates kvt 2 (lo) / 3 (hi)
            unsigned c0 = __shfl(pk2[0], srclA, 64), d0 = __shfl(pk3[0], srclA, 64);
            unsigned c1 = __shfl(pk2[1], srclA, 64), d1 = __shfl(pk3[1], srclA, 64);
            unsigned c2 = __shfl(pk2[0], srclB, 64), d2 = __shfl(pk3[0], srclB, 64);
            unsigned c3 = __shfl(pk2[1], srclB, 64), d3 = __shfl(pk3[1], srclB, 64);
            P.u[0] = hi ? d0 : c0;  P.u[1] = hi ? d1 : c1;
            P.u[2] = hi ? d2 : c2;  P.u[3] = hi ? d3 : c3;
            pfrag[1] = P.v;
        }

        // ---- PV: oacc[dt] += V^T-frag x P-frag (accumulate over w) ----
        #pragma unroll
        for (int w = 0; w < 2; w++)
            #pragma unroll
            for (int dt = 0; dt < 4; dt++) {
                const int row = dt * 16 + l16;
                bf16x8 vf = *(const bf16x8*)((const char*)&Vs[buf][0] + row * 128 +
                                             ((w * 64 + lg4 * 16) ^ ((row & 7) << 4)));
                oacc[dt] = __builtin_amdgcn_mfma_f32_16x16x32_bf16(vf, pfrag[w], oacc[dt], 0, 0, 0);
            }
    };

    for (int tt = 0; tt < NT_; tt += 2) {
        tile(tt,     mA, mB);
        tile(tt + 1, mB, mA);
    }

    // ---- epilogue: full l across lane groups, O[q][d] = O^T/l ----
    l_run += __shfl_xor(l_run, 16, 64);
    l_run += __shfl_xor(l_run, 32, 64);
    const float inv = 1.0f / l_run;
    unsigned short* aoq = ao + ((size_t)(bz * S_ + q)) * H_ + h * HD_;
    #pragma unroll
    for (int dt = 0; dt < 4; dt++) {
        us4 o = { f2bf(oacc[dt][0] * inv), f2bf(oacc[dt][1] * inv),
                  f2bf(oacc[dt][2] * inv), f2bf(oacc[dt][3] * inv) };
        *(us4*)&aoq[dt * 16 + lg4 * 4] = o;
    }
}

// ---------------------------------------------------------------------------
extern "C" void kernel_launch(void* const* d_in, const int* in_sizes, int n_in,
                              void* d_out, int out_size, void* d_ws, size_t ws_size,
                              hipStream_t stream)
{
    (void)in_sizes; (void)n_in; (void)out_size; (void)ws_size;

    const float* query = (const float*)d_in[0];
    const float* key   = (const float*)d_in[1];
    const float* value = (const float*)d_in[2];
    const float* mask  = (const float*)d_in[3];
    const float* Wq    = (const float*)d_in[4];
    const float* bq    = (const float*)d_in[5];
    const float* Wk    = (const float*)d_in[6];
    const float* bk    = (const float*)d_in[7];
    const float* Wv    = (const float*)d_in[8];
    const float* bv    = (const float*)d_in[9];
    const float* Wo    = (const float*)d_in[10];
    const float* bo    = (const float*)d_in[11];

    unsigned short* ws = (unsigned short*)d_ws;
    const size_t MH = (size_t)MM * H_;       // 4 Mi elems
    const size_t WW = (size_t)H_ * H_;       // 1 Mi elems
    unsigned short* Xq  = ws;
    unsigned short* Xk  = Xq + MH;
    unsigned short* Xv  = Xk + MH;
    unsigned short* Wtq = Xv + MH;
    unsigned short* Wtk = Wtq + WW;
    unsigned short* Wtv = Wtk + WW;
    unsigned short* Wto = Wtv + WW;
    unsigned short* qh  = Wto + WW;
    unsigned short* kh  = qh + MH;
    unsigned short* vt  = kh + MH;
    unsigned short* ao  = vt + MH;

    const int n8 = (int)(MH / 8);            // 524288
    cvt_bf16_3<<<dim3(n8 / 256, 3), 256, 0, stream>>>(query, key, value, Xq, Xk, Xv, n8);
    wtr_kernel<<<dim3(32, 32, 4), 256, 0, stream>>>(Wq, Wk, Wv, Wo, Wtq, Wtk, Wtv, Wto);

    gemm_qkv<<<dim3(8, 32, 3), 256, 0, stream>>>(Xq, Xk, Xv, Wtq, Wtk, Wtv,
                                                 bq, bk, bv, qh, kh, vt, 0.125f * LOG2E);

    mfma_attn<<<dim3(S_ / 64, NH_, NB_), 256, 0, stream>>>(qh, kh, vt, mask, ao);

    gemm_out<<<dim3(8, 32), 256, 0, stream>>>(ao, Wto, bo, (float*)d_out);
}